// Round 1
// baseline (384.136 us; speedup 1.0000x reference)
//
#include <hip/hip_runtime.h>
#include <math.h>

#define NF   5
#define NH1  128
#define NH2  32
#define BLK  256

// One thread per row. Streams h1: per k computes h1[k] then updates the 64
// (x21|x22) accumulators, so h1 never occupies 128 registers.
// All weight indices are lane-uniform -> compiler emits s_load into SGPRs;
// the inner loop is v_fmac_f32 with SGPR weight operands.
__global__ __launch_bounds__(BLK, 4) void barriernet_kernel(
    const float* __restrict__ x,
    const float* __restrict__ mean,
    const float* __restrict__ stdv,
    const float* __restrict__ W1,  const float* __restrict__ b1,
    const float* __restrict__ W21, const float* __restrict__ b21,
    const float* __restrict__ W22, const float* __restrict__ b22,
    const float* __restrict__ W31, const float* __restrict__ b31,
    const float* __restrict__ W32, const float* __restrict__ b32,
    float* __restrict__ out)
{
    __shared__ float xs[BLK * NF];
    const int row0 = blockIdx.x * BLK;

    // Coalesced stage of this block's x rows into LDS.
    #pragma unroll
    for (int t = threadIdx.x; t < BLK * NF; t += BLK)
        xs[t] = x[(long)row0 * NF + t];
    __syncthreads();

    float xv[NF];
    #pragma unroll
    for (int f = 0; f < NF; ++f) xv[f] = xs[threadIdx.x * NF + f];

    // Layer-2 accumulators (x21 / x22 pre-relu), kept in VGPRs.
    float acc1[NH2], acc2[NH2];
    #pragma unroll
    for (int j = 0; j < NH2; ++j) { acc1[j] = b21[j]; acc2[j] = b22[j]; }

    #pragma unroll 4
    for (int k = 0; k < NH1; ++k) {
        float h = b1[k];
        #pragma unroll
        for (int f = 0; f < NF; ++f) h = fmaf(xv[f], W1[k * NF + f], h);
        h = fmaxf(h, 0.0f);                       // h1[k]
        #pragma unroll
        for (int j = 0; j < NH2; ++j) {
            acc1[j] = fmaf(h, W21[j * NH1 + k], acc1[j]);
            acc2[j] = fmaf(h, W22[j * NH1 + k], acc2[j]);
        }
    }

    // Heads: x31 (linear), x32 = 4*sigmoid(.)
    float x31 = b31[0];
    float z32 = b32[0];
    #pragma unroll
    for (int j = 0; j < NH2; ++j) {
        x31 = fmaf(fmaxf(acc1[j], 0.0f), W31[j], x31);
        z32 = fmaf(fmaxf(acc2[j], 0.0f), W32[j], z32);
    }
    const float x32 = 4.0f / (1.0f + __expf(-z32));

    // CBF epilogue + closed-form 1-D QP.
    float x0[NF];
    #pragma unroll
    for (int f = 0; f < NF; ++f) x0[f] = fmaf(xv[f], stdv[f], mean[f]);
    const float h_ineq = (x0[1] - x0[3]) + x32 * (x0[0] - x0[2] - 1.8f * x0[3]);
    const float u_unc  = -x31;
    const float u      = (1.8f * u_unc <= h_ineq) ? u_unc : (h_ineq / 1.8f);

    out[row0 + threadIdx.x] = u;
}

extern "C" void kernel_launch(void* const* d_in, const int* in_sizes, int n_in,
                              void* d_out, int out_size, void* d_ws, size_t ws_size,
                              hipStream_t stream) {
    const float* x    = (const float*)d_in[0];
    const float* mean = (const float*)d_in[1];
    const float* stdv = (const float*)d_in[2];
    const float* W1   = (const float*)d_in[3];
    const float* b1   = (const float*)d_in[4];
    const float* W21  = (const float*)d_in[5];
    const float* b21  = (const float*)d_in[6];
    const float* W22  = (const float*)d_in[7];
    const float* b22  = (const float*)d_in[8];
    const float* W31  = (const float*)d_in[9];
    const float* b31  = (const float*)d_in[10];
    const float* W32  = (const float*)d_in[11];
    const float* b32  = (const float*)d_in[12];
    float* out = (float*)d_out;

    const int nrows = in_sizes[0] / NF;       // 524288
    const int grid  = nrows / BLK;            // 2048

    barriernet_kernel<<<grid, BLK, 0, stream>>>(
        x, mean, stdv, W1, b1, W21, b21, W22, b22, W31, b31, W32, b32, out);
}